// Round 9
// baseline (221.167 us; speedup 1.0000x reference)
//
#include <hip/hip_runtime.h>
#include <hip/hip_bf16.h>
#include <math.h>

#define N_NODES 50000
#define K_NEI   32
#define D_FEAT  128
#define LEAKY   0.01f

#define NBLK    2048                   // exactly one co-resident generation @8/CU
#define GPB     8                      // 32-lane groups per 256-thread block
#define NGROUPS (NBLK * GPB)           // 16384 groups
#define NPG     3                      // base nodes per group: 16384*3 = 49152
#define NBASE   (NGROUPS * NPG)        // 49152
#define NEXTRA  (N_NODES - NBASE)      // 848, spread evenly across groups

#define CHUNK_SHIFT 12                 // 4096 rows = 1 MB bf16 per chunk
#define NCHUNKS     ((N_NODES + (1 << CHUNK_SHIFT) - 1) >> CHUNK_SHIFT)   // 13

__device__ __forceinline__ unsigned short f2bf(float x) {
    __hip_bfloat16 b = __float2bfloat16(x);   // RNE
    union { __hip_bfloat16 b; unsigned short u; } c; c.b = b;
    return c.u;
}

// ---------- Phase 1: g = feat.a_nei, h = feat.a_ref, fb = bf16(feat) ----------
__global__ __launch_bounds__(256) void precompute_kernel(
    const float* __restrict__ feat,
    const float* __restrict__ att,
    unsigned short* __restrict__ fb,
    float* __restrict__ g,
    float* __restrict__ h)
{
    const int lane = threadIdx.x & 31;
    const int row  = blockIdx.x * 8 + (threadIdx.x >> 5);
    if (row >= N_NODES) return;

    const float4 a_ref = *(const float4*)&att[4 * lane];
    const float4 a_nei = *(const float4*)&att[D_FEAT + 4 * lane];
    const float4 f     = *(const float4*)&feat[(size_t)row * D_FEAT + 4 * lane];

    float sr = f.x * a_ref.x + f.y * a_ref.y + f.z * a_ref.z + f.w * a_ref.w;
    float sn = f.x * a_nei.x + f.y * a_nei.y + f.z * a_nei.z + f.w * a_nei.w;
    #pragma unroll
    for (int off = 16; off >= 1; off >>= 1) {
        sr += __shfl_xor(sr, off, 32);
        sn += __shfl_xor(sn, off, 32);
    }
    if (lane == 0) { h[row] = sr; g[row] = sn; }

    ushort4 u;
    u.x = f2bf(f.x); u.y = f2bf(f.y); u.z = f2bf(f.z); u.w = f2bf(f.w);
    *(ushort4*)&fb[(size_t)row * D_FEAT + 4 * lane] = u;
}

// ---------- Phase 2: LDS rank-sorted pairs, flat fixed-trip gather ----------
__global__ __launch_bounds__(256, 8) void gather_lds(
    const unsigned short* __restrict__ fb,
    const int*   __restrict__ nei,
    const float* __restrict__ g,
    const float* __restrict__ h,
    float*       __restrict__ out)
{
    __shared__ uint2 pairs[GPB][NPG + 1][K_NEI];   // 8 KB: (nk, w) chunk-sorted

    const int lane       = threadIdx.x & 31;
    const int grp        = threadIdx.x >> 5;           // 0..7
    const int group      = blockIdx.x * GPB + grp;     // 0..16383
    const int half_shift = threadIdx.x & 32;
    const unsigned lt    = (1u << lane) - 1u;

    // extra (4th) node for ~every 19th group, evenly spread
    const bool has4  = (((group + 1) * NEXTRA) >> 14) != ((group * NEXTRA) >> 14);
    const int  node3 = NBASE + ((group * NEXTRA) >> 14);

    // ---- setup: weights + chunk-sort rank, scatter (nk,w) into LDS ----
    #pragma unroll
    for (int j = 0; j < NPG + 1; ++j) {
        if (j == NPG && !has4) continue;          // skip absent 4th node
        const int node = (j < NPG) ? (group * NPG + j) : node3;

        const int idx = nei[node * K_NEI + lane];
        float sc = h[node] + g[idx];
        sc = (sc >= 0.f) ? sc : LEAKY * sc;
        const float p = __expf(sc);        // no-max softmax: |score| small, f32-safe
        float denom = p;
        #pragma unroll
        for (int off = 16; off >= 1; off >>= 1)
            denom += __shfl_xor(denom, off, 32);
        const float w = p / denom;

        const int cid = idx >> CHUNK_SHIFT;
        int rank = 0;
        #pragma unroll
        for (int c = 0; c < NCHUNKS; ++c) {
            const unsigned long long b = __ballot(cid == c);
            const unsigned bh = (unsigned)(b >> half_shift);
            rank += (c < cid)  ? __popc(bh)      : 0;
            rank += (c == cid) ? __popc(bh & lt) : 0;
        }
        pairs[grp][j][rank] = make_uint2((unsigned)idx, __float_as_uint(w));
    }
    __syncthreads();

    // ---- flat, divergence-free gather in (approx) chunk order ----
    float4 o[NPG + 1];
    #pragma unroll
    for (int j = 0; j < NPG + 1; ++j) o[j] = make_float4(0.f, 0.f, 0.f, 0.f);

    const unsigned loff = (unsigned)(lane << 2);   // ushort element offset in row

    #pragma unroll 8
    for (int i = 0; i < K_NEI; ++i) {
        #pragma unroll
        for (int j = 0; j < NPG; ++j) {
            const uint2 t  = pairs[grp][j][i];     // uniform LDS broadcast
            const float wk = __uint_as_float(t.y);
            const uint2 v  = *(const uint2*)&fb[(t.x << 7) + loff];
            o[j].x += wk * __uint_as_float(v.x << 16);
            o[j].y += wk * __uint_as_float(v.x & 0xFFFF0000u);
            o[j].z += wk * __uint_as_float(v.y << 16);
            o[j].w += wk * __uint_as_float(v.y & 0xFFFF0000u);
        }
        if (has4) {                                // predicated 4th node
            const uint2 t  = pairs[grp][NPG][i];
            const float wk = __uint_as_float(t.y);
            const uint2 v  = *(const uint2*)&fb[(t.x << 7) + loff];
            o[NPG].x += wk * __uint_as_float(v.x << 16);
            o[NPG].y += wk * __uint_as_float(v.x & 0xFFFF0000u);
            o[NPG].z += wk * __uint_as_float(v.y << 16);
            o[NPG].w += wk * __uint_as_float(v.y & 0xFFFF0000u);
        }
    }

    #pragma unroll
    for (int j = 0; j < NPG + 1; ++j) {
        if (j == NPG && !has4) continue;
        const int node = (j < NPG) ? (group * NPG + j) : node3;
        float4 r;
        r.x = (o[j].x > 0.f) ? o[j].x : expm1f(o[j].x);
        r.y = (o[j].y > 0.f) ? o[j].y : expm1f(o[j].y);
        r.z = (o[j].z > 0.f) ? o[j].z : expm1f(o[j].z);
        r.w = (o[j].w > 0.f) ? o[j].w : expm1f(o[j].w);
        *(float4*)&out[(size_t)node * D_FEAT + 4 * lane] = r;
    }
}

// ---------- Fallback (round-1 kernel) if workspace too small ----------
__global__ __launch_bounds__(256, 4) void feat_encoder_fallback(
    const float* __restrict__ feat,
    const int*   __restrict__ nei,
    const float* __restrict__ att,
    float*       __restrict__ out)
{
    const int lane = threadIdx.x & 31;
    const int node = blockIdx.x * 8 + (threadIdx.x >> 5);
    if (node >= N_NODES) return;

    const float4 a_ref = *(const float4*)&att[4 * lane];
    const float4 a_nei = *(const float4*)&att[D_FEAT + 4 * lane];

    const float4 f = *(const float4*)&feat[(size_t)node * D_FEAT + 4 * lane];
    float sref = f.x * a_ref.x + f.y * a_ref.y + f.z * a_ref.z + f.w * a_ref.w;
    #pragma unroll
    for (int off = 16; off >= 1; off >>= 1)
        sref += __shfl_xor(sref, off, 32);

    const int idx = nei[node * K_NEI + lane];
    float  s = 0.f;
    float4 o = {0.f, 0.f, 0.f, 0.f};
    #pragma unroll
    for (int k = 0; k < K_NEI; ++k) {
        const int nk = __shfl(idx, k, 32);
        const float4 v = *(const float4*)&feat[(size_t)nk * D_FEAT + 4 * lane];
        float partial = v.x * a_nei.x + v.y * a_nei.y + v.z * a_nei.z + v.w * a_nei.w;
        #pragma unroll
        for (int off = 16; off >= 1; off >>= 1)
            partial += __shfl_xor(partial, off, 32);
        float score = partial + sref;
        score = (score >= 0.f) ? score : LEAKY * score;
        const float p = __expf(score);
        s += p;
        o.x += p * v.x; o.y += p * v.y; o.z += p * v.z; o.w += p * v.w;
    }
    const float inv = 1.0f / s;
    float4 r;
    r.x = o.x * inv; r.y = o.y * inv; r.z = o.z * inv; r.w = o.w * inv;
    r.x = (r.x > 0.f) ? r.x : expm1f(r.x);
    r.y = (r.y > 0.f) ? r.y : expm1f(r.y);
    r.z = (r.z > 0.f) ? r.z : expm1f(r.z);
    r.w = (r.w > 0.f) ? r.w : expm1f(r.w);
    *(float4*)&out[(size_t)node * D_FEAT + 4 * lane] = r;
}

extern "C" void kernel_launch(void* const* d_in, const int* in_sizes, int n_in,
                              void* d_out, int out_size, void* d_ws, size_t ws_size,
                              hipStream_t stream) {
    const float* feat = (const float*)d_in[0];
    const int*   nei  = (const int*)d_in[1];
    const float* att  = (const float*)d_in[2];
    float*       out  = (float*)d_out;

    const size_t fb_bytes = (size_t)N_NODES * D_FEAT * sizeof(unsigned short); // 12.8 MB
    const size_t g_bytes  = (size_t)N_NODES * sizeof(float);                   // 200 KB
    const size_t need     = fb_bytes + 2 * g_bytes;

    if (ws_size >= need) {
        unsigned short* fb = (unsigned short*)d_ws;
        float* g = (float*)((char*)d_ws + fb_bytes);
        float* h = (float*)((char*)d_ws + fb_bytes + g_bytes);
        precompute_kernel<<<dim3((N_NODES + 7) / 8), 256, 0, stream>>>(feat, att, fb, g, h);
        gather_lds<<<dim3(NBLK), 256, 0, stream>>>(fb, nei, g, h, out);
    } else {
        feat_encoder_fallback<<<dim3((N_NODES + 7) / 8), 256, 0, stream>>>(feat, nei, att, out);
    }
}

// Round 10
// 60.979 us; speedup vs baseline: 3.6269x; 3.6269x over previous
//
#include <hip/hip_runtime.h>
#include <hip/hip_fp16.h>
#include <math.h>

#define N_NODES 50000
#define K_NEI   32
#define D_FEAT  128
#define LEAKY   0.01f

#define NPG  2                         // nodes per 32-lane group
#define GPB  8                         // 32-lane groups per 256-thread block
#define NPB  (NPG * GPB)               // 16 nodes per block
#define GRID (N_NODES / NPB)           // 3125 blocks exactly (50000 = 3125*16)

#define CHUNK_SHIFT 12                 // 4096 rows = 2 MB per chunk
#define NCHUNKS     ((N_NODES + (1 << CHUNK_SHIFT) - 1) >> CHUNK_SHIFT)   // 13

// ---------- Phase 1: g = feat.a_nei, h = feat.a_ref, fh = f16(feat) ----------
__global__ __launch_bounds__(256) void precompute_kernel(
    const float* __restrict__ feat,
    const float* __restrict__ att,
    unsigned short* __restrict__ fh,
    float* __restrict__ g,
    float* __restrict__ h)
{
    const int lane = threadIdx.x & 31;
    const int row  = blockIdx.x * 8 + (threadIdx.x >> 5);
    if (row >= N_NODES) return;

    const float4 a_ref = *(const float4*)&att[4 * lane];
    const float4 a_nei = *(const float4*)&att[D_FEAT + 4 * lane];
    const float4 f     = *(const float4*)&feat[(size_t)row * D_FEAT + 4 * lane];

    float sr = f.x * a_ref.x + f.y * a_ref.y + f.z * a_ref.z + f.w * a_ref.w;
    float sn = f.x * a_nei.x + f.y * a_nei.y + f.z * a_nei.z + f.w * a_nei.w;
    #pragma unroll
    for (int off = 16; off >= 1; off >>= 1) {
        sr += __shfl_xor(sr, off, 32);
        sn += __shfl_xor(sn, off, 32);
    }
    if (lane == 0) { h[row] = sr; g[row] = sn; }

    // pack 4 f32 -> 4 f16 (RN) and store 8 B
    const __half2 p0 = __floats2half2_rn(f.x, f.y);
    const __half2 p1 = __floats2half2_rn(f.z, f.w);
    uint2 st;
    st.x = *(const unsigned*)&p0;
    st.y = *(const unsigned*)&p1;
    *(uint2*)&fh[(size_t)row * D_FEAT + 4 * lane] = st;
}

// ---------- Phase 2: LDS rank-sorted pairs, flat fixed-trip f16 gather -------
__global__ __launch_bounds__(256, 8) void gather_lds(
    const unsigned short* __restrict__ fh,
    const int*   __restrict__ nei,
    const float* __restrict__ g,
    const float* __restrict__ h,
    float*       __restrict__ out)
{
    // pairs4[grp][rank] = {idx0, w0, idx1, w1}  (j=0,1 side by side -> b128 read)
    __shared__ uint4 pairs4[GPB][K_NEI];   // 4 KB

    const int lane       = threadIdx.x & 31;
    const int grp        = threadIdx.x >> 5;       // 0..7
    const int group      = blockIdx.x * GPB + grp;
    const int half_shift = threadIdx.x & 32;       // 0 lower half, 32 upper half
    const int node0      = group * NPG;
    const unsigned lt    = (1u << lane) - 1u;

    // ---- setup: weights + chunk-sort rank, scatter (idx,w) into LDS ----
    #pragma unroll
    for (int j = 0; j < NPG; ++j) {
        const int node = node0 + j;                // grid covers N exactly

        const int idx = nei[node * K_NEI + lane];
        float sc = h[node] + g[idx];
        sc = (sc >= 0.f) ? sc : LEAKY * sc;
        const float p = __expf(sc);          // no-max softmax: |score| small, f32-safe
        float denom = p;
        #pragma unroll
        for (int off = 16; off >= 1; off >>= 1)
            denom += __shfl_xor(denom, off, 32);
        const float w = p / denom;

        const int cid = idx >> CHUNK_SHIFT;
        int rank = 0;
        #pragma unroll
        for (int c = 0; c < NCHUNKS; ++c) {
            const unsigned long long b = __ballot(cid == c);
            const unsigned bh = (unsigned)(b >> half_shift);
            rank += (c < cid)  ? __popc(bh)      : 0;
            rank += (c == cid) ? __popc(bh & lt) : 0;
        }
        ((uint2*)&pairs4[grp][rank])[j] = make_uint2((unsigned)idx, __float_as_uint(w));
    }
    __syncthreads();

    // ---- flat, divergence-free gather in (approx) chunk order ----
    float4 o0 = make_float4(0.f, 0.f, 0.f, 0.f);
    float4 o1 = make_float4(0.f, 0.f, 0.f, 0.f);

    const unsigned lbyte = (unsigned)(lane << 3);  // byte offset of this lane's 8 B
    const char* fbase = (const char*)fh;

    #pragma unroll 8
    for (int i = 0; i < K_NEI; ++i) {
        const uint4 t = pairs4[grp][i];            // one ds_read_b128, uniform bcast
        const float w0 = __uint_as_float(t.y);
        const float w1 = __uint_as_float(t.w);
        const uint2 v0 = *(const uint2*)(fbase + ((t.x << 8) + lbyte));
        const uint2 v1 = *(const uint2*)(fbase + ((t.z << 8) + lbyte));

        const __half2 a0 = *(const __half2*)&v0.x;
        const __half2 a1 = *(const __half2*)&v0.y;
        const __half2 b0 = *(const __half2*)&v1.x;
        const __half2 b1 = *(const __half2*)&v1.y;

        o0.x += w0 * __half2float(a0.x);   // v_fma_mix_f32
        o0.y += w0 * __half2float(a0.y);
        o0.z += w0 * __half2float(a1.x);
        o0.w += w0 * __half2float(a1.y);
        o1.x += w1 * __half2float(b0.x);
        o1.y += w1 * __half2float(b0.y);
        o1.z += w1 * __half2float(b1.x);
        o1.w += w1 * __half2float(b1.y);
    }

    // ---- ELU + store ----
    {
        float4 r;
        r.x = (o0.x > 0.f) ? o0.x : expm1f(o0.x);
        r.y = (o0.y > 0.f) ? o0.y : expm1f(o0.y);
        r.z = (o0.z > 0.f) ? o0.z : expm1f(o0.z);
        r.w = (o0.w > 0.f) ? o0.w : expm1f(o0.w);
        *(float4*)&out[(size_t)(node0 + 0) * D_FEAT + 4 * lane] = r;
        r.x = (o1.x > 0.f) ? o1.x : expm1f(o1.x);
        r.y = (o1.y > 0.f) ? o1.y : expm1f(o1.y);
        r.z = (o1.z > 0.f) ? o1.z : expm1f(o1.z);
        r.w = (o1.w > 0.f) ? o1.w : expm1f(o1.w);
        *(float4*)&out[(size_t)(node0 + 1) * D_FEAT + 4 * lane] = r;
    }
}

// ---------- Fallback (round-1 kernel) if workspace too small ----------
__global__ __launch_bounds__(256, 4) void feat_encoder_fallback(
    const float* __restrict__ feat,
    const int*   __restrict__ nei,
    const float* __restrict__ att,
    float*       __restrict__ out)
{
    const int lane = threadIdx.x & 31;
    const int node = blockIdx.x * 8 + (threadIdx.x >> 5);
    if (node >= N_NODES) return;

    const float4 a_ref = *(const float4*)&att[4 * lane];
    const float4 a_nei = *(const float4*)&att[D_FEAT + 4 * lane];

    const float4 f = *(const float4*)&feat[(size_t)node * D_FEAT + 4 * lane];
    float sref = f.x * a_ref.x + f.y * a_ref.y + f.z * a_ref.z + f.w * a_ref.w;
    #pragma unroll
    for (int off = 16; off >= 1; off >>= 1)
        sref += __shfl_xor(sref, off, 32);

    const int idx = nei[node * K_NEI + lane];
    float  s = 0.f;
    float4 o = {0.f, 0.f, 0.f, 0.f};
    #pragma unroll
    for (int k = 0; k < K_NEI; ++k) {
        const int nk = __shfl(idx, k, 32);
        const float4 v = *(const float4*)&feat[(size_t)nk * D_FEAT + 4 * lane];
        float partial = v.x * a_nei.x + v.y * a_nei.y + v.z * a_nei.z + v.w * a_nei.w;
        #pragma unroll
        for (int off = 16; off >= 1; off >>= 1)
            partial += __shfl_xor(partial, off, 32);
        float score = partial + sref;
        score = (score >= 0.f) ? score : LEAKY * score;
        const float p = __expf(score);
        s += p;
        o.x += p * v.x; o.y += p * v.y; o.z += p * v.z; o.w += p * v.w;
    }
    const float inv = 1.0f / s;
    float4 r;
    r.x = o.x * inv; r.y = o.y * inv; r.z = o.z * inv; r.w = o.w * inv;
    r.x = (r.x > 0.f) ? r.x : expm1f(r.x);
    r.y = (r.y > 0.f) ? r.y : expm1f(r.y);
    r.z = (r.z > 0.f) ? r.z : expm1f(r.z);
    r.w = (r.w > 0.f) ? r.w : expm1f(r.w);
    *(float4*)&out[(size_t)node * D_FEAT + 4 * lane] = r;
}

extern "C" void kernel_launch(void* const* d_in, const int* in_sizes, int n_in,
                              void* d_out, int out_size, void* d_ws, size_t ws_size,
                              hipStream_t stream) {
    const float* feat = (const float*)d_in[0];
    const int*   nei  = (const int*)d_in[1];
    const float* att  = (const float*)d_in[2];
    float*       out  = (float*)d_out;

    const size_t fh_bytes = (size_t)N_NODES * D_FEAT * sizeof(unsigned short); // 12.8 MB
    const size_t g_bytes  = (size_t)N_NODES * sizeof(float);                   // 200 KB
    const size_t need     = fh_bytes + 2 * g_bytes;

    if (ws_size >= need) {
        unsigned short* fh = (unsigned short*)d_ws;
        float* g = (float*)((char*)d_ws + fh_bytes);
        float* h = (float*)((char*)d_ws + fh_bytes + g_bytes);
        precompute_kernel<<<dim3((N_NODES + 7) / 8), 256, 0, stream>>>(feat, att, fh, g, h);
        gather_lds<<<dim3(GRID), 256, 0, stream>>>(fh, nei, g, h, out);
    } else {
        feat_encoder_fallback<<<dim3((N_NODES + 7) / 8), 256, 0, stream>>>(feat, nei, att, out);
    }
}